// Round 1
// baseline (1497.406 us; speedup 1.0000x reference)
//
#include <hip/hip_runtime.h>
#include <stdint.h>

#define MDIM 8192
#define NDIM 11008
#define KDIM 4096
#define BM 128
#define BN 128
#define BK 32

typedef __bf16 bf16x8 __attribute__((ext_vector_type(8)));
typedef float floatx4 __attribute__((ext_vector_type(4)));

typedef const __attribute__((address_space(1))) void* gas_ptr;
typedef __attribute__((address_space(3))) void* las_ptr;

__device__ __forceinline__ unsigned short f32_bf16_rne(float f) {
    union { float f; unsigned u; } v; v.f = f;
    unsigned r = 0x7FFFu + ((v.u >> 16) & 1u);
    return (unsigned short)((v.u + r) >> 16);
}

// ---- pass 1: x fp32 -> bf16, 8 elems/thread, exact grid (M*K/8/256 blocks) ----
__global__ __launch_bounds__(256) void convert_x_kernel(
    const float* __restrict__ x, unsigned short* __restrict__ xb)
{
    const size_t gid = (size_t)blockIdx.x * 256 + threadIdx.x;
    const float4* p = (const float4*)x + gid * 2;
    float4 a = p[0], b = p[1];
    unsigned short t[8];
    t[0] = f32_bf16_rne(a.x); t[1] = f32_bf16_rne(a.y);
    t[2] = f32_bf16_rne(a.z); t[3] = f32_bf16_rne(a.w);
    t[4] = f32_bf16_rne(b.x); t[5] = f32_bf16_rne(b.y);
    t[6] = f32_bf16_rne(b.z); t[7] = f32_bf16_rne(b.w);
    *(uint4*)(xb + gid * 8) = *(const uint4*)t;
}

// ---- pass 2: qweight int32 -> dequantized bf16, 8 elems/thread ----
__global__ __launch_bounds__(256) void dequant_w_kernel(
    const int* __restrict__ q, const float* __restrict__ scales,
    const float* __restrict__ zps, unsigned short* __restrict__ wb)
{
    const size_t gid = (size_t)blockIdx.x * 256 + threadIdx.x;
    const int o = (int)(gid >> 9);           // 512 groups of 8 per row of 4096
    const float s = scales[o], z = zps[o];
    const int4* p = (const int4*)q + gid * 2;
    int4 a = p[0], b = p[1];
    unsigned short t[8];
    t[0] = f32_bf16_rne(((float)a.x - z) * s);
    t[1] = f32_bf16_rne(((float)a.y - z) * s);
    t[2] = f32_bf16_rne(((float)a.z - z) * s);
    t[3] = f32_bf16_rne(((float)a.w - z) * s);
    t[4] = f32_bf16_rne(((float)b.x - z) * s);
    t[5] = f32_bf16_rne(((float)b.y - z) * s);
    t[6] = f32_bf16_rne(((float)b.z - z) * s);
    t[7] = f32_bf16_rne(((float)b.w - z) * s);
    *(uint4*)(wb + gid * 8) = *(const uint4*)t;
}

// ---- pass 3: m97-structure bf16 GEMM, C = A * B^T + bias ----
// A[M,K] bf16, B[N,K] bf16 (K contiguous both), C[M,N] fp32.
__global__ __launch_bounds__(256) void gemm_bf16_kernel(
    const unsigned short* __restrict__ A,
    const unsigned short* __restrict__ B,
    const float* __restrict__ bias,
    float* __restrict__ C)
{
    __shared__ __align__(16) unsigned short As[BM * BK];  // 8 KB
    __shared__ __align__(16) unsigned short Bs[BN * BK];  // 8 KB

    const int tid  = threadIdx.x;
    const int lane = tid & 63;
    const int wave = tid >> 6;           // 0..3 -> 2x2 wave grid of 64x64
    const int wm   = (wave >> 1) * 64;
    const int wn   = (wave & 1) * 64;
    const int bm   = blockIdx.y * BM;
    const int bn   = blockIdx.x * BN;

    floatx4 acc[4][4];
#pragma unroll
    for (int i = 0; i < 4; ++i)
#pragma unroll
        for (int j = 0; j < 4; ++j)
            acc[i][j] = (floatx4){0.f, 0.f, 0.f, 0.f};

    const int mrow = lane & 15;
    const int kq   = (lane >> 4) * 8;

    // staging: 512 16B-chunks per tile (128 rows x 4 chunks); chunk c -> row c>>2, k (c&3)*8
    // lane l of wave w in round t handles chunk t*256 + w*64 + l; LDS dest is
    // wave-uniform base + lane*16 (global_load_lds HW rule).
    const int c0 = tid, c1 = tid + 256;
    const int r0 = c0 >> 2, k0c = (c0 & 3) * 8;
    const int r1 = c1 >> 2, k1c = (c1 & 3) * 8;
    const unsigned short* gA0 = A + (size_t)(bm + r0) * KDIM + k0c;
    const unsigned short* gA1 = A + (size_t)(bm + r1) * KDIM + k1c;
    const unsigned short* gB0 = B + (size_t)(bn + r0) * KDIM + k0c;
    const unsigned short* gB1 = B + (size_t)(bn + r1) * KDIM + k1c;
    unsigned short* lA0 = As + (wave * 64) * 8;
    unsigned short* lA1 = As + (256 + wave * 64) * 8;
    unsigned short* lB0 = Bs + (wave * 64) * 8;
    unsigned short* lB1 = Bs + (256 + wave * 64) * 8;

    for (int kt = 0; kt < KDIM; kt += BK) {
        __builtin_amdgcn_global_load_lds((gas_ptr)(gA0 + kt), (las_ptr)lA0, 16, 0, 0);
        __builtin_amdgcn_global_load_lds((gas_ptr)(gA1 + kt), (las_ptr)lA1, 16, 0, 0);
        __builtin_amdgcn_global_load_lds((gas_ptr)(gB0 + kt), (las_ptr)lB0, 16, 0, 0);
        __builtin_amdgcn_global_load_lds((gas_ptr)(gB1 + kt), (las_ptr)lB1, 16, 0, 0);
        __syncthreads();   // drains vmcnt before barrier (compiler-inserted)

        bf16x8 af[4], bfr[4];
#pragma unroll
        for (int i = 0; i < 4; ++i)
            af[i] = *(const bf16x8*)(As + (wm + i * 16 + mrow) * BK + kq);
#pragma unroll
        for (int j = 0; j < 4; ++j)
            bfr[j] = *(const bf16x8*)(Bs + (wn + j * 16 + mrow) * BK + kq);
#pragma unroll
        for (int i = 0; i < 4; ++i)
#pragma unroll
            for (int j = 0; j < 4; ++j)
                acc[i][j] = __builtin_amdgcn_mfma_f32_16x16x32_bf16(
                    af[i], bfr[j], acc[i][j], 0, 0, 0);
        __syncthreads();
    }

    // epilogue: C/D layout col=lane&15, row=(lane>>4)*4+reg
#pragma unroll
    for (int j = 0; j < 4; ++j) {
        const int col = bn + wn + j * 16 + mrow;
        const float bv = bias[col];
#pragma unroll
        for (int i = 0; i < 4; ++i) {
            const int rbase = bm + wm + i * 16 + (lane >> 4) * 4;
#pragma unroll
            for (int r = 0; r < 4; ++r)
                C[(size_t)(rbase + r) * NDIM + col] = acc[i][j][r] + bv;
        }
    }
}

// ---- fallback if ws too small: same tile structure, register-staged dequant ----
__global__ __launch_bounds__(256) void gemm_fused_fallback(
    const float* __restrict__ X, const int* __restrict__ Q,
    const float* __restrict__ scales, const float* __restrict__ zps,
    const float* __restrict__ bias, float* __restrict__ C)
{
    __shared__ __align__(16) unsigned short As[BM * BK];
    __shared__ __align__(16) unsigned short Bs[BN * BK];

    const int tid  = threadIdx.x;
    const int lane = tid & 63;
    const int wave = tid >> 6;
    const int wm   = (wave >> 1) * 64;
    const int wn   = (wave & 1) * 64;
    const int bm   = blockIdx.y * BM;
    const int bn   = blockIdx.x * BN;

    floatx4 acc[4][4];
#pragma unroll
    for (int i = 0; i < 4; ++i)
#pragma unroll
        for (int j = 0; j < 4; ++j)
            acc[i][j] = (floatx4){0.f, 0.f, 0.f, 0.f};

    const int mrow = lane & 15;
    const int kq   = (lane >> 4) * 8;

    for (int kt = 0; kt < KDIM; kt += BK) {
#pragma unroll
        for (int s4 = 0; s4 < 4; ++s4) {
            const int c = tid + 256 * s4;      // 1024 4-elem chunks per tile
            const int row = c >> 3, kc = (c & 7) * 4;
            float4 xv = *(const float4*)(X + (size_t)(bm + row) * KDIM + kt + kc);
            unsigned short ta[4];
            ta[0] = f32_bf16_rne(xv.x); ta[1] = f32_bf16_rne(xv.y);
            ta[2] = f32_bf16_rne(xv.z); ta[3] = f32_bf16_rne(xv.w);
            *(uint2*)(As + row * BK + kc) = *(const uint2*)ta;

            int4 qv = *(const int4*)(Q + (size_t)(bn + row) * KDIM + kt + kc);
            const float sc = scales[bn + row], z = zps[bn + row];
            unsigned short tb[4];
            tb[0] = f32_bf16_rne(((float)qv.x - z) * sc);
            tb[1] = f32_bf16_rne(((float)qv.y - z) * sc);
            tb[2] = f32_bf16_rne(((float)qv.z - z) * sc);
            tb[3] = f32_bf16_rne(((float)qv.w - z) * sc);
            *(uint2*)(Bs + row * BK + kc) = *(const uint2*)tb;
        }
        __syncthreads();

        bf16x8 af[4], bfr[4];
#pragma unroll
        for (int i = 0; i < 4; ++i)
            af[i] = *(const bf16x8*)(As + (wm + i * 16 + mrow) * BK + kq);
#pragma unroll
        for (int j = 0; j < 4; ++j)
            bfr[j] = *(const bf16x8*)(Bs + (wn + j * 16 + mrow) * BK + kq);
#pragma unroll
        for (int i = 0; i < 4; ++i)
#pragma unroll
            for (int j = 0; j < 4; ++j)
                acc[i][j] = __builtin_amdgcn_mfma_f32_16x16x32_bf16(
                    af[i], bfr[j], acc[i][j], 0, 0, 0);
        __syncthreads();
    }

#pragma unroll
    for (int j = 0; j < 4; ++j) {
        const int col = bn + wn + j * 16 + mrow;
        const float bv = bias[col];
#pragma unroll
        for (int i = 0; i < 4; ++i) {
            const int rbase = bm + wm + i * 16 + (lane >> 4) * 4;
#pragma unroll
            for (int r = 0; r < 4; ++r)
                C[(size_t)(rbase + r) * NDIM + col] = acc[i][j][r] + bv;
        }
    }
}

extern "C" void kernel_launch(void* const* d_in, const int* in_sizes, int n_in,
                              void* d_out, int out_size, void* d_ws, size_t ws_size,
                              hipStream_t stream) {
    const float* x  = (const float*)d_in[0];
    const int*   qw = (const int*)d_in[1];
    const float* sc = (const float*)d_in[2];
    const float* zp = (const float*)d_in[3];
    const float* bs = (const float*)d_in[4];
    float* out = (float*)d_out;

    const size_t needA = (size_t)MDIM * KDIM * sizeof(unsigned short); // 64 MiB
    const size_t needW = (size_t)NDIM * KDIM * sizeof(unsigned short); // 86 MiB
    dim3 grid(NDIM / BN, MDIM / BM);  // 86 x 64

    if (ws_size >= needA + needW) {
        unsigned short* xb = (unsigned short*)d_ws;
        unsigned short* wb = (unsigned short*)((char*)d_ws + needA);
        convert_x_kernel<<<dim3(MDIM * KDIM / (8 * 256)), dim3(256), 0, stream>>>(x, xb);
        dequant_w_kernel<<<dim3(NDIM * KDIM / (8 * 256)), dim3(256), 0, stream>>>(qw, sc, zp, wb);
        gemm_bf16_kernel<<<grid, dim3(256), 0, stream>>>(xb, wb, bs, out);
    } else {
        gemm_fused_fallback<<<grid, dim3(256), 0, stream>>>(x, qw, sc, zp, bs, out);
    }
}

// Round 2
// 1438.447 us; speedup vs baseline: 1.0410x; 1.0410x over previous
//
#include <hip/hip_runtime.h>
#include <stdint.h>

#define MDIM 8192
#define NDIM 11008
#define KDIM 4096
#define BM 128
#define BN 128
#define BK 32

typedef __bf16 bf16x8 __attribute__((ext_vector_type(8)));
typedef float floatx4 __attribute__((ext_vector_type(4)));

typedef const __attribute__((address_space(1))) void* gas_ptr;
typedef __attribute__((address_space(3))) void* las_ptr;

__device__ __forceinline__ unsigned short f32_bf16_rne(float f) {
    union { float f; unsigned u; } v; v.f = f;
    unsigned r = 0x7FFFu + ((v.u >> 16) & 1u);
    return (unsigned short)((v.u + r) >> 16);
}

// ---- pass 1: x fp32 -> bf16, 8 elems/thread ----
__global__ __launch_bounds__(256) void convert_x_kernel(
    const float* __restrict__ x, unsigned short* __restrict__ xb)
{
    const size_t gid = (size_t)blockIdx.x * 256 + threadIdx.x;
    const float4* p = (const float4*)x + gid * 2;
    float4 a = p[0], b = p[1];
    unsigned short t[8];
    t[0] = f32_bf16_rne(a.x); t[1] = f32_bf16_rne(a.y);
    t[2] = f32_bf16_rne(a.z); t[3] = f32_bf16_rne(a.w);
    t[4] = f32_bf16_rne(b.x); t[5] = f32_bf16_rne(b.y);
    t[6] = f32_bf16_rne(b.z); t[7] = f32_bf16_rne(b.w);
    *(uint4*)(xb + gid * 8) = *(const uint4*)t;
}

// ---- pass 2: qweight int32 -> dequantized bf16, 8 elems/thread ----
__global__ __launch_bounds__(256) void dequant_w_kernel(
    const int* __restrict__ q, const float* __restrict__ scales,
    const float* __restrict__ zps, unsigned short* __restrict__ wb)
{
    const size_t gid = (size_t)blockIdx.x * 256 + threadIdx.x;
    const int o = (int)(gid >> 9);           // 512 groups of 8 per row of 4096
    const float s = scales[o], z = zps[o];
    const int4* p = (const int4*)q + gid * 2;
    int4 a = p[0], b = p[1];
    unsigned short t[8];
    t[0] = f32_bf16_rne(((float)a.x - z) * s);
    t[1] = f32_bf16_rne(((float)a.y - z) * s);
    t[2] = f32_bf16_rne(((float)a.z - z) * s);
    t[3] = f32_bf16_rne(((float)a.w - z) * s);
    t[4] = f32_bf16_rne(((float)b.x - z) * s);
    t[5] = f32_bf16_rne(((float)b.y - z) * s);
    t[6] = f32_bf16_rne(((float)b.z - z) * s);
    t[7] = f32_bf16_rne(((float)b.w - z) * s);
    *(uint4*)(wb + gid * 8) = *(const uint4*)t;
}

// ---- pass 3: bf16 GEMM, C = A * B^T + bias ----
// A[M,K] bf16, B[N,K] bf16 (K contiguous both), C[M,N] fp32.
// Grid: blockIdx.x = M-tile (fastest -> concurrent blocks share B panels,
// A stays L3-resident), blockIdx.y = N-tile.
// LDS layout XOR-swizzled: slot (row, c) holds global k-chunk c ^ (row&3),
// breaking the 64B-row-stride bank aliasing while keeping the
// global_load_lds contiguous-destination rule intact.
__global__ __launch_bounds__(256) void gemm_bf16_kernel(
    const unsigned short* __restrict__ A,
    const unsigned short* __restrict__ B,
    const float* __restrict__ bias,
    float* __restrict__ C)
{
    __shared__ __align__(16) unsigned short As[BM * BK];  // 8 KB
    __shared__ __align__(16) unsigned short Bs[BN * BK];  // 8 KB

    const int tid  = threadIdx.x;
    const int lane = tid & 63;
    const int wave = tid >> 6;           // 0..3 -> 2x2 wave grid of 64x64
    const int wm   = (wave >> 1) * 64;
    const int wn   = (wave & 1) * 64;
    const int bm   = blockIdx.x * BM;    // M fastest
    const int bn   = blockIdx.y * BN;

    floatx4 acc[4][4];
#pragma unroll
    for (int i = 0; i < 4; ++i)
#pragma unroll
        for (int j = 0; j < 4; ++j)
            acc[i][j] = (floatx4){0.f, 0.f, 0.f, 0.f};

    const int mrow = lane & 15;
    const int kc   = lane >> 4;                 // k-chunk index 0..3
    const int ks   = ((kc ^ (mrow & 3)) * 8);   // swizzled k-slot (elems)

    // staging: 512 16B-chunks per tile; LDS slot c (contiguous, tid-ordered)
    // holds row c>>2, global k-chunk (c&3)^(row&3).
    const int c0 = tid, c1 = tid + 256;
    const int r0 = c0 >> 2, k0c = (((c0 & 3) ^ (r0 & 3)) * 8);
    const int r1 = c1 >> 2, k1c = (((c1 & 3) ^ (r1 & 3)) * 8);
    const unsigned short* gA0 = A + (size_t)(bm + r0) * KDIM + k0c;
    const unsigned short* gA1 = A + (size_t)(bm + r1) * KDIM + k1c;
    const unsigned short* gB0 = B + (size_t)(bn + r0) * KDIM + k0c;
    const unsigned short* gB1 = B + (size_t)(bn + r1) * KDIM + k1c;
    unsigned short* lA0 = As + (wave * 64) * 8;
    unsigned short* lA1 = As + (256 + wave * 64) * 8;
    unsigned short* lB0 = Bs + (wave * 64) * 8;
    unsigned short* lB1 = Bs + (256 + wave * 64) * 8;

    for (int kt = 0; kt < KDIM; kt += BK) {
        __builtin_amdgcn_global_load_lds((gas_ptr)(gA0 + kt), (las_ptr)lA0, 16, 0, 0);
        __builtin_amdgcn_global_load_lds((gas_ptr)(gA1 + kt), (las_ptr)lA1, 16, 0, 0);
        __builtin_amdgcn_global_load_lds((gas_ptr)(gB0 + kt), (las_ptr)lB0, 16, 0, 0);
        __builtin_amdgcn_global_load_lds((gas_ptr)(gB1 + kt), (las_ptr)lB1, 16, 0, 0);
        __syncthreads();

        bf16x8 af[4], bfr[4];
#pragma unroll
        for (int i = 0; i < 4; ++i)
            af[i] = *(const bf16x8*)(As + (wm + i * 16 + mrow) * BK + ks);
#pragma unroll
        for (int j = 0; j < 4; ++j)
            bfr[j] = *(const bf16x8*)(Bs + (wn + j * 16 + mrow) * BK + ks);
#pragma unroll
        for (int i = 0; i < 4; ++i)
#pragma unroll
            for (int j = 0; j < 4; ++j)
                acc[i][j] = __builtin_amdgcn_mfma_f32_16x16x32_bf16(
                    af[i], bfr[j], acc[i][j], 0, 0, 0);
        __syncthreads();
    }

    // epilogue: C/D layout col=lane&15, row=(lane>>4)*4+reg
#pragma unroll
    for (int j = 0; j < 4; ++j) {
        const int col = bn + wn + j * 16 + mrow;
        const float bv = bias[col];
#pragma unroll
        for (int i = 0; i < 4; ++i) {
            const int rbase = bm + wm + i * 16 + (lane >> 4) * 4;
#pragma unroll
            for (int r = 0; r < 4; ++r)
                C[(size_t)(rbase + r) * NDIM + col] = acc[i][j][r] + bv;
        }
    }
}

// ---- fallback if ws too small: same tile structure, register-staged dequant ----
__global__ __launch_bounds__(256) void gemm_fused_fallback(
    const float* __restrict__ X, const int* __restrict__ Q,
    const float* __restrict__ scales, const float* __restrict__ zps,
    const float* __restrict__ bias, float* __restrict__ C)
{
    __shared__ __align__(16) unsigned short As[BM * BK];
    __shared__ __align__(16) unsigned short Bs[BN * BK];

    const int tid  = threadIdx.x;
    const int lane = tid & 63;
    const int wave = tid >> 6;
    const int wm   = (wave >> 1) * 64;
    const int wn   = (wave & 1) * 64;
    const int bm   = blockIdx.x * BM;
    const int bn   = blockIdx.y * BN;

    floatx4 acc[4][4];
#pragma unroll
    for (int i = 0; i < 4; ++i)
#pragma unroll
        for (int j = 0; j < 4; ++j)
            acc[i][j] = (floatx4){0.f, 0.f, 0.f, 0.f};

    const int mrow = lane & 15;
    const int kq   = (lane >> 4) * 8;

    for (int kt = 0; kt < KDIM; kt += BK) {
#pragma unroll
        for (int s4 = 0; s4 < 4; ++s4) {
            const int c = tid + 256 * s4;
            const int row = c >> 3, kcb = (c & 7) * 4;
            float4 xv = *(const float4*)(X + (size_t)(bm + row) * KDIM + kt + kcb);
            unsigned short ta[4];
            ta[0] = f32_bf16_rne(xv.x); ta[1] = f32_bf16_rne(xv.y);
            ta[2] = f32_bf16_rne(xv.z); ta[3] = f32_bf16_rne(xv.w);
            *(uint2*)(As + row * BK + kcb) = *(const uint2*)ta;

            int4 qv = *(const int4*)(Q + (size_t)(bn + row) * KDIM + kt + kcb);
            const float sc = scales[bn + row], z = zps[bn + row];
            unsigned short tb[4];
            tb[0] = f32_bf16_rne(((float)qv.x - z) * sc);
            tb[1] = f32_bf16_rne(((float)qv.y - z) * sc);
            tb[2] = f32_bf16_rne(((float)qv.z - z) * sc);
            tb[3] = f32_bf16_rne(((float)qv.w - z) * sc);
            *(uint2*)(Bs + row * BK + kcb) = *(const uint2*)tb;
        }
        __syncthreads();

        bf16x8 af[4], bfr[4];
#pragma unroll
        for (int i = 0; i < 4; ++i)
            af[i] = *(const bf16x8*)(As + (wm + i * 16 + mrow) * BK + kq);
#pragma unroll
        for (int j = 0; j < 4; ++j)
            bfr[j] = *(const bf16x8*)(Bs + (wn + j * 16 + mrow) * BK + kq);
#pragma unroll
        for (int i = 0; i < 4; ++i)
#pragma unroll
            for (int j = 0; j < 4; ++j)
                acc[i][j] = __builtin_amdgcn_mfma_f32_16x16x32_bf16(
                    af[i], bfr[j], acc[i][j], 0, 0, 0);
        __syncthreads();
    }

#pragma unroll
    for (int j = 0; j < 4; ++j) {
        const int col = bn + wn + j * 16 + mrow;
        const float bv = bias[col];
#pragma unroll
        for (int i = 0; i < 4; ++i) {
            const int rbase = bm + wm + i * 16 + (lane >> 4) * 4;
#pragma unroll
            for (int r = 0; r < 4; ++r)
                C[(size_t)(rbase + r) * NDIM + col] = acc[i][j][r] + bv;
        }
    }
}

extern "C" void kernel_launch(void* const* d_in, const int* in_sizes, int n_in,
                              void* d_out, int out_size, void* d_ws, size_t ws_size,
                              hipStream_t stream) {
    const float* x  = (const float*)d_in[0];
    const int*   qw = (const int*)d_in[1];
    const float* sc = (const float*)d_in[2];
    const float* zp = (const float*)d_in[3];
    const float* bs = (const float*)d_in[4];
    float* out = (float*)d_out;

    const size_t needA = (size_t)MDIM * KDIM * sizeof(unsigned short); // 64 MiB
    const size_t needW = (size_t)NDIM * KDIM * sizeof(unsigned short); // 86 MiB
    dim3 grid(MDIM / BM, NDIM / BN);  // 64 x 86, M fastest

    if (ws_size >= needA + needW) {
        unsigned short* xb = (unsigned short*)d_ws;
        unsigned short* wb = (unsigned short*)((char*)d_ws + needA);
        convert_x_kernel<<<dim3(MDIM * KDIM / (8 * 256)), dim3(256), 0, stream>>>(x, xb);
        dequant_w_kernel<<<dim3(NDIM * KDIM / (8 * 256)), dim3(256), 0, stream>>>(qw, sc, zp, wb);
        gemm_bf16_kernel<<<grid, dim3(256), 0, stream>>>(xb, wb, bs, out);
    } else {
        gemm_fused_fallback<<<grid, dim3(256), 0, stream>>>(x, qw, sc, zp, bs, out);
    }
}